// Round 5
// baseline (981.749 us; speedup 1.0000x reference)
//
#include <hip/hip_runtime.h>
#include <hip/hip_bf16.h>

typedef short short8 __attribute__((ext_vector_type(8)));
typedef short short4v __attribute__((ext_vector_type(4)));
typedef float f32x4 __attribute__((ext_vector_type(4)));

static __device__ __forceinline__ short f2bf(float f){
  __hip_bfloat16 h = __float2bfloat16(f);
  return __builtin_bit_cast(short, h);
}
static __device__ __forceinline__ float b2f(short s){
  unsigned int u = ((unsigned int)(unsigned short)s) << 16;
  return __builtin_bit_cast(float, u);
}
static __device__ __forceinline__ float lrelu(float x){ return x > 0.f ? x : 0.2f*x; }
static __device__ __forceinline__ float eluf(float x){ return x > 0.f ? x : (__expf(x)-1.f); }
static __device__ __forceinline__ int imin(int a,int b){ return a<b?a:b; }

typedef const __attribute__((address_space(1))) void as1_void;
typedef __attribute__((address_space(3))) void as3_void;
static __device__ __forceinline__ void gload16(const void* g, void* l){
  __builtin_amdgcn_global_load_lds((as1_void*)g, (as3_void*)l, 16, 0, 0);
}
template<int NN> __device__ __forceinline__ void wait_vm(){
  if constexpr (NN==0) asm volatile("s_waitcnt vmcnt(0)" ::: "memory");
  else if constexpr (NN==1) asm volatile("s_waitcnt vmcnt(1)" ::: "memory");
  else if constexpr (NN==3) asm volatile("s_waitcnt vmcnt(3)" ::: "memory");
  else if constexpr (NN==5) asm volatile("s_waitcnt vmcnt(5)" ::: "memory");
}

// ==================== GEMM: reg-staged A (f32+affine+ELU or bf16), B gload_lds ====================
// 512 thr = 8 waves (4 wm x 2 wn). BM=64, BN=128, BK=32. Ring-4 A(ds_write) + B(gload).
// A f32: [M][lda] with optional affine from (a_sum,a_sq,a_g,a_bt,invM). Bt bf16 [NR][ldb] zero-padded.
template<bool AF32, bool AFF, bool OBF16, bool CST>
__global__ __launch_bounds__(512, 4) void gemm_r(
    const void* __restrict__ Av, int lda, const short* __restrict__ Bt, int ldb,
    void* __restrict__ Cv, int ldc, const float* __restrict__ bias,
    int M, int N, int K,
    const float* __restrict__ a_sum, const float* __restrict__ a_sq,
    const float* __restrict__ a_g, const float* __restrict__ a_bt, float invM,
    float* __restrict__ o_sum, float* __restrict__ o_sq)
{
  constexpr int BM=64, BN=128, BK=32;
  __shared__ short Asm[4][BM*BK];   // 4KB each
  __shared__ short Bsm[4][BN*BK];   // 8KB each
  __shared__ float s_sc[256], s_sh[256];

  const int tid = threadIdx.x, wid = tid>>6, lane = tid&63;
  const int wm = wid>>1, wn = wid&1;
  const int bm = blockIdx.x*BM, bn = blockIdx.y*BN;
  const int lr = lane&15, lg = lane>>4;
  const int nt = (K + BK - 1)/BK;
  const float* A32 = (const float*)Av;
  const short* A16 = (const short*)Av;

  // A-stage geometry: chunk c=tid -> row 0-63, g 0-7 (4-element granule)
  const int arow = tid>>3, ag = tid&7;
  const int agr  = imin(bm + arow, M-1);
  const int awr  = arow*BK + (((ag>>1) ^ (arow&3))<<3) + (ag&1)*4;  // swizzled shorts offset
  // B-stage geometry: chunk c=tid -> row 0-127, g 0-3 (8-short granule), pre-swizzled source
  const int brow = tid>>2, bg = tid&3;
  const short* bptr = Bt + (size_t)(bn+brow)*ldb + ((bg ^ (brow&3))<<3);

  f32x4 acc[4] = {};
  float4  raf[4];
  short4v ras[4];

  #define ISSUE(T, S) do{                                                     \
    if ((T) < nt){                                                            \
      int k_ = (T)*BK + ag*4;                                                 \
      if (AF32){ int kk_ = imin(k_, K-4);                                     \
        raf[S] = *(const float4*)(A32 + (size_t)agr*lda + kk_); }             \
      else { ras[S] = *(const short4v*)(A16 + (size_t)agr*lda + k_); }        \
      gload16(bptr + (size_t)(T)*BK, (void*)&Bsm[S][wid*512]);                \
    } }while(0)

  #define WRA(T, S) do{                                                       \
    if ((T) < nt){                                                            \
      short4v o_;                                                             \
      if (AF32){                                                              \
        float4 f_ = raf[S];                                                   \
        if (AFF){ int k0_ = (T)*BK + ag*4;                                    \
          float4 sc_ = *(const float4*)&s_sc[k0_];                            \
          float4 sh_ = *(const float4*)&s_sh[k0_];                            \
          f_.x = eluf(f_.x*sc_.x+sh_.x); f_.y = eluf(f_.y*sc_.y+sh_.y);       \
          f_.z = eluf(f_.z*sc_.z+sh_.z); f_.w = eluf(f_.w*sc_.w+sh_.w); }     \
        o_[0]=f2bf(f_.x); o_[1]=f2bf(f_.y); o_[2]=f2bf(f_.z); o_[3]=f2bf(f_.w);\
      } else { o_ = ras[S]; }                                                 \
      *(short4v*)&Asm[S][awr] = o_;                                           \
    } }while(0)

  #define BODY(T, S, SW, SI) do{                                              \
    if ((T) < nt){                                                            \
      if ((T)+2 < nt) wait_vm<3>(); else if ((T)+1 < nt) wait_vm<1>();        \
      else wait_vm<0>();                                                      \
      WRA((T)+1, SW);                                                         \
      asm volatile("s_waitcnt lgkmcnt(0)" ::: "memory");                      \
      __builtin_amdgcn_sched_barrier(0);                                      \
      __builtin_amdgcn_s_barrier();                                           \
      __builtin_amdgcn_sched_barrier(0);                                      \
      int ra_ = wm*16 + lr;                                                   \
      short8 af_ = *(short8*)&Asm[S][ra_*BK + ((lg ^ (ra_&3))<<3)];           \
      short8 bf_[4];                                                          \
      _Pragma("unroll")                                                       \
      for (int n_=0;n_<4;n_++){ int rb_ = wn*64 + n_*16 + lr;                 \
        bf_[n_] = *(short8*)&Bsm[S][rb_*BK + ((lg ^ (rb_&3))<<3)]; }          \
      ISSUE((T)+3, SI);                                                       \
      _Pragma("unroll")                                                       \
      for (int n_=0;n_<4;n_++)                                                \
        acc[n_] = __builtin_amdgcn_mfma_f32_16x16x32_bf16(af_, bf_[n_], acc[n_], 0,0,0); \
    } }while(0)

  // ---- prologue ----
  ISSUE(0,0); ISSUE(1,1); ISSUE(2,2);
  if (AFF){
    for (int k = tid; k < K; k += 512){
      float mn = a_sum[k]*invM;
      float vr = a_sq[k]*invM - mn*mn;
      float s  = a_g[k]*rsqrtf(vr + 1e-5f);
      s_sc[k] = s; s_sh[k] = a_bt[k] - mn*s;
    }
    asm volatile("s_waitcnt lgkmcnt(0)" ::: "memory");
    __builtin_amdgcn_sched_barrier(0);
    __builtin_amdgcn_s_barrier();
  }
  if (nt >= 3) wait_vm<5>(); else if (nt == 2) wait_vm<3>(); else wait_vm<1>();
  WRA(0, 0);
  asm volatile("s_waitcnt lgkmcnt(0)" ::: "memory");
  __builtin_amdgcn_sched_barrier(0);
  __builtin_amdgcn_s_barrier();
  __builtin_amdgcn_sched_barrier(0);

  for (int t = 0; t < nt; t += 4){
    BODY(t+0, 0, 1, 3);
    BODY(t+1, 1, 2, 0);
    BODY(t+2, 2, 3, 1);
    BODY(t+3, 3, 0, 2);
  }
  #undef ISSUE
  #undef WRA
  #undef BODY

  // ---- epilogue ----
  const int rowb = bm + wm*16 + lg*4;
  #pragma unroll
  for (int n=0;n<4;n++){
    int col = bn + wn*64 + n*16 + lr;
    #pragma unroll
    for (int q=0;q<4;q++){
      int row = rowb + q;
      if (row < M && col < N){
        float v = acc[n][q];
        if (bias) v += bias[col];
        if (OBF16) ((short*)Cv)[(size_t)row*ldc + col] = f2bf(v);
        else       ((float*)Cv)[(size_t)row*ldc + col] = v;
      }
    }
  }
  if (CST){
    #pragma unroll
    for (int n=0;n<4;n++){
      float s = 0.f, q2 = 0.f;
      #pragma unroll
      for (int q=0;q<4;q++){
        int row = rowb + q;
        if (row < M){ float v = acc[n][q]; s += v; q2 += v*v; }
      }
      s  += __shfl_xor(s, 16);  s += __shfl_xor(s, 32);
      q2 += __shfl_xor(q2, 16); q2 += __shfl_xor(q2, 32);
      if (lg == 0){
        int col = bn + wn*64 + n*16 + lr;
        if (col < N){ atomicAdd(&o_sum[col], s); atomicAdd(&o_sq[col], q2); }
      }
    }
  }
}

// ==================== weight transpose/convert ====================
struct WEnt { const float* src; short* dst; int K, N, KP, NR; };
struct WTab { WEnt e[12]; };
__global__ __launch_bounds__(256) void wtrans_all(WTab tab){
  WEnt w = tab.e[blockIdx.y];
  int gid = blockIdx.x*256 + threadIdx.x;
  if (gid >= w.NR * w.KP) return;
  int n = gid / w.KP, k = gid - n*w.KP;
  float v = (k < w.K && n < w.N) ? w.src[(size_t)k*w.N + n] : 0.f;
  w.dst[gid] = f2bf(v);
}

// ==================== CSR build ====================
__global__ void hist_kernel(const int* __restrict__ d, int E, int* __restrict__ deg){
  int i = blockIdx.x*256 + threadIdx.x;
  if (i < E) atomicAdd(&deg[d[i]], 1);
}
__global__ __launch_bounds__(256) void scan1(const int* __restrict__ deg, int* __restrict__ offs,
                                             int* __restrict__ bsum, int n){
  __shared__ int sm[256];
  int tid = threadIdx.x;
  int base = blockIdx.x*1024 + tid*4;
  int v0 = base+0<n ? deg[base+0] : 0;
  int v1 = base+1<n ? deg[base+1] : 0;
  int v2 = base+2<n ? deg[base+2] : 0;
  int v3 = base+3<n ? deg[base+3] : 0;
  int ts = v0+v1+v2+v3;
  sm[tid] = ts;
  __syncthreads();
  #pragma unroll
  for (int d=1; d<256; d<<=1){
    int t = (tid>=d) ? sm[tid-d] : 0;
    __syncthreads();
    sm[tid] += t;
    __syncthreads();
  }
  int ex = sm[tid] - ts;
  if (base+0<n) offs[base+0] = ex;
  if (base+1<n) offs[base+1] = ex+v0;
  if (base+2<n) offs[base+2] = ex+v0+v1;
  if (base+3<n) offs[base+3] = ex+v0+v1+v2;
  if (tid==255) bsum[blockIdx.x] = sm[255];
}
__global__ __launch_bounds__(256) void scan3(int* __restrict__ offs, const int* __restrict__ bsum,
                      int* __restrict__ cursor, int n, int total){
  __shared__ int base_sm;
  int tgt = blockIdx.x >> 2;
  if (threadIdx.x < 64){
    int j = threadIdx.x;
    int v = (j < tgt) ? bsum[j] : 0;
    #pragma unroll
    for (int d=32; d; d>>=1) v += __shfl_xor(v, d);
    if (j == 0) base_sm = v;
  }
  __syncthreads();
  int i = blockIdx.x*256 + threadIdx.x;
  if (i < n){ int v = offs[i] + base_sm; offs[i]=v; cursor[i]=v; }
  if (i == 0) offs[n] = total;
}
__global__ void scatter_kernel(const int* __restrict__ s, const int* __restrict__ d, int E,
                               int* __restrict__ cursor, int* __restrict__ csr){
  int i = blockIdx.x*256 + threadIdx.x;
  if (i < E){ int pos = atomicAdd(&cursor[d[i]], 1); csr[pos] = s[i]; }
}

// ==================== GAT1 ====================
__global__ __launch_bounds__(256) void gat1_scores_bf(const short* __restrict__ hh,
    const float* __restrict__ as, const float* __restrict__ ad,
    float* __restrict__ ss, float* __restrict__ sd, int n){
  int w = threadIdx.x >> 6, lane = threadIdx.x & 63;
  int row = blockIdx.x*4 + w;
  if (row >= n) return;
  const short* hr = hh + (size_t)row*192;
  float ps[3], pd[3];
  #pragma unroll
  for (int h=0; h<3; h++){
    float v = b2f(hr[h*64 + lane]);
    ps[h] = v * as[h*64+lane];
    pd[h] = v * ad[h*64+lane];
  }
  #pragma unroll
  for (int m=32; m; m>>=1){
    #pragma unroll
    for (int h=0;h<3;h++){ ps[h] += __shfl_xor(ps[h], m); pd[h] += __shfl_xor(pd[h], m); }
  }
  if (lane == 0){
    #pragma unroll
    for (int h=0;h<3;h++){ ss[row*3+h]=ps[h]; sd[row*3+h]=pd[h]; }
  }
}

__global__ __launch_bounds__(256) void gat1_gather_bf(const int* __restrict__ offs, const int* __restrict__ csr,
    const short* __restrict__ hh, const float* __restrict__ ss, const float* __restrict__ sd,
    const float* __restrict__ bias, short* __restrict__ out, int n){
  int w = threadIdx.x >> 6, lane = threadIdx.x & 63;
  int dst = blockIdx.x*4 + w;
  if (dst >= n) return;
  float sd0 = sd[dst*3+0], sd1 = sd[dst*3+1], sd2 = sd[dst*3+2];
  float p0 = __expf(lrelu(ss[dst*3+0]+sd0));
  float p1 = __expf(lrelu(ss[dst*3+1]+sd1));
  float p2 = __expf(lrelu(ss[dst*3+2]+sd2));
  const short* hr = hh + (size_t)dst*192;
  float a0 = p0*b2f(hr[lane]), a1 = p1*b2f(hr[64+lane]), a2 = p2*b2f(hr[128+lane]);
  float d0 = p0, d1 = p1, d2 = p2;
  int p = offs[dst], pe = offs[dst+1];
  int n0=0,n1=0,n2=0,n3=0;
  if (p+4 <= pe){ n0=csr[p]; n1=csr[p+1]; n2=csr[p+2]; n3=csr[p+3]; }
  while (p+4 <= pe){
    int s0=n0, s1=n1, s2=n2, s3=n3;
    int pn = p+4;
    if (pn+4 <= pe){ n0=csr[pn]; n1=csr[pn+1]; n2=csr[pn+2]; n3=csr[pn+3]; }
    float e00=ss[s0*3+0], e01=ss[s0*3+1], e02=ss[s0*3+2];
    float e10=ss[s1*3+0], e11=ss[s1*3+1], e12=ss[s1*3+2];
    float e20=ss[s2*3+0], e21=ss[s2*3+1], e22=ss[s2*3+2];
    float e30=ss[s3*3+0], e31=ss[s3*3+1], e32=ss[s3*3+2];
    const short* r0 = hh + (size_t)s0*192;
    const short* r1 = hh + (size_t)s1*192;
    const short* r2 = hh + (size_t)s2*192;
    const short* r3 = hh + (size_t)s3*192;
    float v00=b2f(r0[lane]), v01=b2f(r0[64+lane]), v02=b2f(r0[128+lane]);
    float v10=b2f(r1[lane]), v11=b2f(r1[64+lane]), v12=b2f(r1[128+lane]);
    float v20=b2f(r2[lane]), v21=b2f(r2[64+lane]), v22=b2f(r2[128+lane]);
    float v30=b2f(r3[lane]), v31=b2f(r3[64+lane]), v32=b2f(r3[128+lane]);
    float q00=__expf(lrelu(e00+sd0)), q01=__expf(lrelu(e01+sd1)), q02=__expf(lrelu(e02+sd2));
    float q10=__expf(lrelu(e10+sd0)), q11=__expf(lrelu(e11+sd1)), q12=__expf(lrelu(e12+sd2));
    float q20=__expf(lrelu(e20+sd0)), q21=__expf(lrelu(e21+sd1)), q22=__expf(lrelu(e22+sd2));
    float q30=__expf(lrelu(e30+sd0)), q31=__expf(lrelu(e31+sd1)), q32=__expf(lrelu(e32+sd2));
    a0 += q00*v00 + q10*v10 + q20*v20 + q30*v30;
    a1 += q01*v01 + q11*v11 + q21*v21 + q31*v31;
    a2 += q02*v02 + q12*v12 + q22*v22 + q32*v32;
    d0 += q00+q10+q20+q30;
    d1 += q01+q11+q21+q31;
    d2 += q02+q12+q22+q32;
    p = pn;
  }
  for (; p < pe; ++p){
    int src = csr[p];
    float q0 = __expf(lrelu(ss[src*3+0]+sd0));
    float q1 = __expf(lrelu(ss[src*3+1]+sd1));
    float q2 = __expf(lrelu(ss[src*3+2]+sd2));
    const short* sr = hh + (size_t)src*192;
    a0 += q0*b2f(sr[lane]); a1 += q1*b2f(sr[64+lane]); a2 += q2*b2f(sr[128+lane]);
    d0 += q0; d1 += q1; d2 += q2;
  }
  float v0 = a0/d0 + bias[lane];
  float v1 = a1/d1 + bias[64+lane];
  float v2 = a2/d2 + bias[128+lane];
  short* orow = out + (size_t)dst*192;
  orow[lane]      = f2bf(v0 > 0.f ? v0 : 0.f);
  orow[64+lane]   = f2bf(v1 > 0.f ? v1 : 0.f);
  orow[128+lane]  = f2bf(v2 > 0.f ? v2 : 0.f);
}

// ==================== GAT2/3 fused (hh23 [N][64]: cols 0-29 = h2, 32-61 = h3) ====================
__global__ __launch_bounds__(256) void gat23_scores(const float* __restrict__ hh23,
    const float* __restrict__ a2s, const float* __restrict__ a2d,
    const float* __restrict__ a3s, const float* __restrict__ a3d,
    float* __restrict__ s2s, float* __restrict__ s2d, float* __restrict__ s3s, float* __restrict__ s3d, int n){
  int w = threadIdx.x >> 6, lane = threadIdx.x & 63;
  int row = blockIdx.x*4 + w;
  if (row >= n) return;
  float p[4] = {0.f,0.f,0.f,0.f};
  if (lane < 30){
    float v2 = hh23[(size_t)row*64+lane], v3 = hh23[(size_t)row*64+32+lane];
    p[0]=v2*a2s[lane]; p[1]=v2*a2d[lane]; p[2]=v3*a3s[lane]; p[3]=v3*a3d[lane];
  }
  #pragma unroll
  for (int m=32; m; m>>=1){
    #pragma unroll
    for (int j=0;j<4;j++) p[j] += __shfl_xor(p[j], m);
  }
  if (lane == 0){ s2s[row]=p[0]; s2d[row]=p[1]; s3s[row]=p[2]; s3d[row]=p[3]; }
}

__global__ __launch_bounds__(256) void gat23_gather(const int* __restrict__ offs, const int* __restrict__ csr,
    const float* __restrict__ hh23,
    const float* __restrict__ s2s, const float* __restrict__ s2d,
    const float* __restrict__ s3s, const float* __restrict__ s3d,
    const float* __restrict__ b2, const float* __restrict__ b3,
    float* __restrict__ zs, float* __restrict__ mus, float* __restrict__ lvs,
    short* __restrict__ zbf, int n){
  int w = threadIdx.x >> 6, lane = threadIdx.x & 63;
  int dst = blockIdx.x*4 + w;
  if (dst >= n) return;
  bool lo = lane < 32;
  int c = lane & 31;
  bool valid = c < 30;
  float sdA = s2d[dst], sdB = s3d[dst];
  float sdx = lo ? sdA : sdB;
  const float* ssx = lo ? s2s : s3s;
  float p2 = __expf(lrelu(s2s[dst]+sdA));
  float p3 = __expf(lrelu(s3s[dst]+sdB));
  float val = valid ? hh23[(size_t)dst*64+lane] : 0.f;
  float acc = (lo ? p2 : p3) * val;
  float den2 = p2, den3 = p3;
  int p = offs[dst], pe = offs[dst+1];
  int n0=0,n1=0,n2=0,n3=0;
  if (p+4 <= pe){ n0=csr[p]; n1=csr[p+1]; n2=csr[p+2]; n3=csr[p+3]; }
  while (p+4 <= pe){
    int s0=n0, s1=n1, s2i=n2, s3i=n3;
    int pn = p+4;
    if (pn+4 <= pe){ n0=csr[pn]; n1=csr[pn+1]; n2=csr[pn+2]; n3=csr[pn+3]; }
    float eA0=ssx[s0], eA1=ssx[s1], eA2=ssx[s2i], eA3=ssx[s3i];
    float f20=s2s[s0], f21=s2s[s1], f22=s2s[s2i], f23=s2s[s3i];
    float f30=s3s[s0], f31=s3s[s1], f32=s3s[s2i], f33=s3s[s3i];
    float v0 = valid ? hh23[(size_t)s0*64+lane] : 0.f;
    float v1 = valid ? hh23[(size_t)s1*64+lane] : 0.f;
    float v2 = valid ? hh23[(size_t)s2i*64+lane] : 0.f;
    float v3 = valid ? hh23[(size_t)s3i*64+lane] : 0.f;
    float qx0=__expf(lrelu(eA0+sdx)), qx1=__expf(lrelu(eA1+sdx));
    float qx2=__expf(lrelu(eA2+sdx)), qx3=__expf(lrelu(eA3+sdx));
    acc += qx0*v0 + qx1*v1 + qx2*v2 + qx3*v3;
    den2 += __expf(lrelu(f20+sdA)) + __expf(lrelu(f21+sdA)) + __expf(lrelu(f22+sdA)) + __expf(lrelu(f23+sdA));
    den3 += __expf(lrelu(f30+sdB)) + __expf(lrelu(f31+sdB)) + __expf(lrelu(f32+sdB)) + __expf(lrelu(f33+sdB));
    p = pn;
  }
  for (; p < pe; ++p){
    int src = csr[p];
    float q2 = __expf(lrelu(s2s[src]+sdA));
    float q3 = __expf(lrelu(s3s[src]+sdB));
    float v = valid ? hh23[(size_t)src*64+lane] : 0.f;
    acc += (lo ? q2 : q3) * v;
    den2 += q2; den3 += q3;
  }
  if (lo){
    if (valid){
      float v = acc/den2 + b2[c];
      zs[(size_t)dst*30+c]  = v;
      mus[(size_t)dst*30+c] = v;
      zbf[(size_t)dst*32+c] = f2bf(v);
    } else {
      zbf[(size_t)dst*32+c] = 0;
    }
  } else if (valid){
    lvs[(size_t)dst*30+c] = acc/den3 + b3[c];
  }
}

// ==================== softmax ====================
__global__ __launch_bounds__(256) void softmax10(const float* __restrict__ in, float* __restrict__ out, int n){
  int row = blockIdx.x*256 + threadIdx.x;
  if (row >= n) return;
  const float* r = in + (size_t)row*10;
  float m = r[0];
  #pragma unroll
  for (int j=1;j<10;j++) m = fmaxf(m, r[j]);
  float e[10], s = 0.f;
  #pragma unroll
  for (int j=0;j<10;j++){ e[j] = __expf(r[j]-m); s += e[j]; }
  float inv = 1.f/s;
  float* o = out + (size_t)row*10;
  #pragma unroll
  for (int j=0;j<10;j++) o[j] = e[j]*inv;
}

// ==================== host ====================
static inline int cdiv(int a, int b){ return (a + b - 1) / b; }

extern "C" void kernel_launch(void* const* d_in, const int* in_sizes, int n_in,
                              void* d_out, int out_size, void* d_ws, size_t ws_size,
                              hipStream_t stream)
{
  const float* x        = (const float*)d_in[0];
  const int*   ei       = (const int*)  d_in[1];
  const float* enc_w1   = (const float*)d_in[2];
  const float* enc_g1   = (const float*)d_in[4];
  const float* enc_bt1  = (const float*)d_in[5];
  const float* enc_w2   = (const float*)d_in[6];
  const float* enc_g2   = (const float*)d_in[8];
  const float* enc_bt2  = (const float*)d_in[9];
  const float* gat1_w   = (const float*)d_in[10];
  const float* gat1_as  = (const float*)d_in[11];
  const float* gat1_ad  = (const float*)d_in[12];
  const float* gat1_b   = (const float*)d_in[13];
  const float* gat2_w   = (const float*)d_in[14];
  const float* gat2_as  = (const float*)d_in[15];
  const float* gat2_ad  = (const float*)d_in[16];
  const float* gat2_b   = (const float*)d_in[17];
  const float* gat3_w   = (const float*)d_in[18];
  const float* gat3_as  = (const float*)d_in[19];
  const float* gat3_ad  = (const float*)d_in[20];
  const float* gat3_b   = (const float*)d_in[21];
  const float* dec_w1   = (const float*)d_in[22];
  const float* dec_g1   = (const float*)d_in[24];
  const float* dec_bt1  = (const float*)d_in[25];
  const float* dec_w2   = (const float*)d_in[26];
  const float* dec_g2   = (const float*)d_in[28];
  const float* dec_bt2  = (const float*)d_in[29];
  const float* dec_w3   = (const float*)d_in[30];
  const float* dec_b3   = (const float*)d_in[31];
  const float* clu_w1   = (const float*)d_in[32];
  const float* clu_g1   = (const float*)d_in[34];
  const float* clu_bt1  = (const float*)d_in[35];
  const float* clu_w2   = (const float*)d_in[36];
  const float* clu_b2   = (const float*)d_in[37];

  const int N = in_sizes[0] / 1000;
  const int E = in_sizes[1] / 2;
  const int* e_src = ei;
  const int* e_dst = ei + E;
  const float invN = 1.f/(float)N;

  float* out  = (float*)d_out;
  float* pred = out;
  float* xrec = out + (size_t)N*10;
  float* zs   = xrec + (size_t)N*1000;
  float* mus  = zs  + (size_t)N*30;
  float* lvs  = mus + (size_t)N*30;

  char* ws = (char*)d_ws;
  size_t off = 0;
  auto alloc = [&](size_t bytes)->char*{
    char* p = ws + off;
    off = (off + bytes + 255) & ~(size_t)255;
    return p;
  };
  short* t_enc1  = (short*)alloc(256*1024*2);
  short* t_enc2  = (short*)alloc(128*256*2);
  short* t_gat1  = (short*)alloc(256*128*2);
  short* t_gat23 = (short*)alloc(128*192*2);
  short* t_dc1   = (short*)alloc(256*32*2);
  short* t_dec2  = (short*)alloc(256*128*2);
  short* t_dec3  = (short*)alloc(1024*256*2);
  short* t_clu2  = (short*)alloc(128*128*2);
  float* h1f   = (float*)alloc((size_t)N*256*4);
  float* h2f   = (float*)alloc((size_t)N*128*4);   // d2f spans h2f..h3b
  short* hh1b  = (short*)alloc((size_t)N*192*2);
  short* h3b   = (short*)alloc((size_t)N*192*2);
  float* hh23f = (float*)alloc((size_t)N*64*4);
  short* zbf   = (short*)alloc((size_t)N*32*2);
  float* ss1   = (float*)alloc((size_t)N*3*4);
  float* sd1   = (float*)alloc((size_t)N*3*4);
  float* s2s   = (float*)alloc((size_t)N*4);
  float* s2d   = (float*)alloc((size_t)N*4);
  float* s3s   = (float*)alloc((size_t)N*4);
  float* s3d   = (float*)alloc((size_t)N*4);
  float* stats = (float*)alloc(2048*4);
  int*   deg   = (int*)alloc((size_t)(N+1)*4);
  int*   offs  = (int*)alloc((size_t)(N+1)*4);
  int*   curp  = (int*)alloc((size_t)(N+1)*4);
  int*   bsum  = (int*)alloc(256*4);
  int*   csr   = (int*)alloc((size_t)E*4);
  // aliases:
  float* dc1f = h1f;              // [N][256] f32, h1f dead after enc2
  float* d2f  = h2f;              // [N][256] f32 spans h2f(25.6M)+hh1b(19.2M)+h3b(19.2M) = 64M >= 51.2M; all dead by dec2
  float* c2   = (float*)zbf;      // [N][10] f32 (2MB <= 3.2MB), zbf dead after dc1
  float* st_enc1 = stats, *st_enc2 = stats+512, *st_dc1 = stats+1024, *st_dec2 = stats+1536;

  // --- weight prep + zeroing ---
  WTab tab;
  tab.e[0]  = {enc_w1, t_enc1, 1000, 256, 1024, 256};
  tab.e[1]  = {enc_w2, t_enc2, 256, 128, 256, 128};
  tab.e[2]  = {gat1_w, t_gat1, 128, 192, 128, 256};
  tab.e[3]  = {gat2_w, t_gat23, 192, 30, 192, 32};
  tab.e[4]  = {gat3_w, t_gat23 + 32*192, 192, 30, 192, 32};
  tab.e[5]  = {gat2_w, t_gat23 + 64*192, 192, 0, 192, 64};   // zero rows 64-127
  tab.e[6]  = {dec_w1, t_dc1, 30, 128, 32, 128};
  tab.e[7]  = {clu_w1, t_dc1 + 128*32, 30, 128, 32, 128};
  tab.e[8]  = {dec_w2, t_dec2, 128, 256, 128, 256};
  tab.e[9]  = {dec_w3, t_dec3, 256, 1000, 256, 1024};
  tab.e[10] = {clu_w2, t_clu2, 128, 10, 128, 128};
  tab.e[11] = {enc_w1, t_enc1, 0, 0, 0, 0};                  // dummy
  wtrans_all<<<dim3(1024, 12), 256, 0, stream>>>(tab);
  hipMemsetAsync(stats, 0, 2048*4, stream);
  hipMemsetAsync(deg, 0, (size_t)(N+1)*4, stream);

  // --- CSR ---
  hist_kernel<<<cdiv(E,256), 256, 0, stream>>>(e_dst, E, deg);
  int nb = cdiv(N, 1024);
  scan1<<<nb, 256, 0, stream>>>(deg, offs, bsum, N);
  scan3<<<cdiv(N,256), 256, 0, stream>>>(offs, bsum, curp, N, E);
  scatter_kernel<<<cdiv(E,256), 256, 0, stream>>>(e_src, e_dst, E, curp, csr);

  const int MB = cdiv(N, 64);   // 782

  // --- encoder L1: direct f32 A ---
  gemm_r<true,false,false,true><<<dim3(MB,2), 512, 0, stream>>>(
      x, 1000, t_enc1, 1024, h1f, 256, nullptr, N, 256, 1000,
      nullptr, nullptr, nullptr, nullptr, 0.f, st_enc1, st_enc1+256);
  // --- encoder L2: A = ELU(BN1(h1f)) fused ---
  gemm_r<true,true,false,true><<<dim3(MB,1), 512, 0, stream>>>(
      h1f, 256, t_enc2, 256, h2f, 128, nullptr, N, 128, 256,
      st_enc1, st_enc1+256, enc_g1, enc_bt1, invN, st_enc2, st_enc2+256);
  // --- GAT1 linear: A = ELU(BN2(h2f)) fused, bf16 out ---
  gemm_r<true,true,true,false><<<dim3(MB,2), 512, 0, stream>>>(
      h2f, 128, t_gat1, 128, hh1b, 192, nullptr, N, 192, 128,
      st_enc2, st_enc2+256, enc_g2, enc_bt2, invN, nullptr, nullptr);
  gat1_scores_bf<<<cdiv(N,4), 256, 0, stream>>>(hh1b, gat1_as, gat1_ad, ss1, sd1, N);
  gat1_gather_bf<<<cdiv(N,4), 256, 0, stream>>>(offs, csr, hh1b, ss1, sd1, gat1_b, h3b, N);

  // --- GAT2+GAT3 linear (combined) ---
  gemm_r<false,false,false,false><<<dim3(MB,1), 512, 0, stream>>>(
      h3b, 192, t_gat23, 192, hh23f, 64, nullptr, N, 64, 192,
      nullptr, nullptr, nullptr, nullptr, 0.f, nullptr, nullptr);
  gat23_scores<<<cdiv(N,4), 256, 0, stream>>>(hh23f, gat2_as, gat2_ad, gat3_as, gat3_ad, s2s, s2d, s3s, s3d, N);
  gat23_gather<<<cdiv(N,4), 256, 0, stream>>>(offs, csr, hh23f, s2s, s2d, s3s, s3d, gat2_b, gat3_b, zs, mus, lvs, zbf, N);

  // --- dec1 + clu1 combined (A = zbf bf16, K=32) ---
  gemm_r<false,false,false,true><<<dim3(MB,2), 512, 0, stream>>>(
      zbf, 32, t_dc1, 32, dc1f, 256, nullptr, N, 256, 32,
      nullptr, nullptr, nullptr, nullptr, 0.f, st_dc1, st_dc1+256);
  // --- dec2: A = ELU(BN(dc1f cols 0-127)) fused ---
  gemm_r<true,true,false,true><<<dim3(MB,2), 512, 0, stream>>>(
      dc1f, 256, t_dec2, 128, d2f, 256, nullptr, N, 256, 128,
      st_dc1, st_dc1+256, dec_g1, dec_bt1, invN, st_dec2, st_dec2+256);
  // --- dec3: A = ELU(BN(d2f)) fused, + bias ---
  gemm_r<true,true,false,false><<<dim3(MB,8), 512, 0, stream>>>(
      d2f, 256, t_dec3, 256, xrec, 1000, dec_b3, N, 1000, 256,
      st_dec2, st_dec2+256, dec_g2, dec_bt2, invN, nullptr, nullptr);
  // --- clu2: A = ELU(BN(dc1f cols 128-255)) fused, + bias ---
  gemm_r<true,true,false,false><<<dim3(MB,1), 512, 0, stream>>>(
      dc1f + 128, 256, t_clu2, 128, c2, 10, clu_b2, N, 10, 128,
      st_dc1+128, st_dc1+256+128, clu_g1, clu_bt1, invN, nullptr, nullptr);
  softmax10<<<cdiv(N,256), 256, 0, stream>>>(c2, pred, N);
}

// Round 6
// 734.042 us; speedup vs baseline: 1.3375x; 1.3375x over previous
//
#include <hip/hip_runtime.h>
#include <hip/hip_bf16.h>

typedef short short8 __attribute__((ext_vector_type(8)));
typedef short short4v __attribute__((ext_vector_type(4)));
typedef float f32x4 __attribute__((ext_vector_type(4)));

static __device__ __forceinline__ short f2bf(float f){
  __hip_bfloat16 h = __float2bfloat16(f);
  return __builtin_bit_cast(short, h);
}
static __device__ __forceinline__ float b2f(short s){
  unsigned int u = ((unsigned int)(unsigned short)s) << 16;
  return __builtin_bit_cast(float, u);
}
static __device__ __forceinline__ float lrelu(float x){ return x > 0.f ? x : 0.2f*x; }
static __device__ __forceinline__ float eluf(float x){ return x > 0.f ? x : (__expf(x)-1.f); }
static __device__ __forceinline__ int imin(int a,int b){ return a<b?a:b; }

typedef const __attribute__((address_space(1))) void as1_void;
typedef __attribute__((address_space(3))) void as3_void;
static __device__ __forceinline__ void gload16(const void* g, void* l){
  __builtin_amdgcn_global_load_lds((as1_void*)g, (as3_void*)l, 16, 0, 0);
}
template<int NN> __device__ __forceinline__ void wait_vm(){
  if constexpr (NN==0) asm volatile("s_waitcnt vmcnt(0)" ::: "memory");
  else if constexpr (NN==4) asm volatile("s_waitcnt vmcnt(4)" ::: "memory");
  else if constexpr (NN==6) asm volatile("s_waitcnt vmcnt(6)" ::: "memory");
  else if constexpr (NN==8) asm volatile("s_waitcnt vmcnt(8)" ::: "memory");
  else if constexpr (NN==12) asm volatile("s_waitcnt vmcnt(12)" ::: "memory");
  else asm volatile("s_waitcnt vmcnt(0)" ::: "memory");
}

// ==================== x f32 -> bf16 convert (streaming) ====================
__global__ __launch_bounds__(256) void cvt_x(const float* __restrict__ x, short* __restrict__ xb, int M){
  int row = blockIdx.x*2 + (threadIdx.x>>7);
  int c8  = (threadIdx.x&127)*8;
  if (row >= M || c8 >= 1000) return;
  const float* p = x + (size_t)row*1000 + c8;
  float4 f0 = *(const float4*)p, f1 = *(const float4*)(p+4);
  short8 o;
  o[0]=f2bf(f0.x);o[1]=f2bf(f0.y);o[2]=f2bf(f0.z);o[3]=f2bf(f0.w);
  o[4]=f2bf(f1.x);o[5]=f2bf(f1.y);o[6]=f2bf(f1.z);o[7]=f2bf(f1.w);
  *(short8*)&xb[(size_t)row*1000 + c8] = o;
}

// ==================== GEMM: gload_lds ring, BK=64, counted vmcnt, 512 thr ====================
// A bf16 [M][lda], Bt bf16 [NR][ldb] zero-padded rows/cols. B zero for k in [K, ceil64(K)).
template<int BN, int BK, int RING, bool OBF16, bool CST>
__global__ __launch_bounds__(512) void gemm_k(
    const short* __restrict__ A, int lda, const short* __restrict__ Bt, int ldb,
    void* __restrict__ Cv, int ldc, const float* __restrict__ bias,
    int M, int N, int K,
    float* __restrict__ o_sum, float* __restrict__ o_sq)
{
  constexpr int BM=128, GPR=BK/8, RPC=64/GPR;      // granules/row, rows/chunk
  constexpr int AI=(BM/RPC)/8, BI=(BN/RPC)/8;      // wave-instrs per stage
  constexpr int LPT=AI+BI, DEPTH=RING-1;
  constexpr int WN=BN/2, FM=2, FN=WN/16, NKK=BK/32;
  static_assert(RING==2 || RING==3, "ring");
  __shared__ short lds[RING][(BM+BN)*BK];

  const int tid=threadIdx.x, wid=tid>>6, lane=tid&63;
  const int wm=wid>>1, wn=wid&1;
  const int bm=blockIdx.x*BM, bn=blockIdx.y*BN;
  const int lr=lane&15, lg=lane>>4;
  const int nt=(K+BK-1)/BK;
  const int l_g = lane & (GPR-1), l_r = lane / GPR;
  f32x4 acc[FM][FN]={};

  #define STG(T,S) do{ if((T)<nt){ int k0_=(T)*BK;                          \
    _Pragma("unroll") for(int i_=0;i_<AI;i_++){                             \
      int ci_=wid*AI+i_; int row_=ci_*RPC+l_r;                              \
      int g_=l_g^(row_&(GPR-1));                                            \
      gload16(A+(size_t)imin(bm+row_,M-1)*lda+k0_+g_*8, (void*)&lds[S][ci_*512]); } \
    _Pragma("unroll") for(int i_=0;i_<BI;i_++){                             \
      int bi_=wid*BI+i_; int row_=bi_*RPC+l_r;                              \
      int g_=l_g^(row_&(GPR-1));                                            \
      gload16(Bt+(size_t)(bn+row_)*ldb+k0_+g_*8, (void*)&lds[S][BM*BK+bi_*512]); } \
  }}while(0)

  #define CMP(S) do{                                                        \
    _Pragma("unroll") for(int kk_=0;kk_<NKK;kk_++){                         \
      short8 af_[FM], bf_[FN];                                              \
      _Pragma("unroll") for(int m_=0;m_<FM;m_++){                           \
        int r_=wm*32+m_*16+lr;                                              \
        af_[m_]=*(short8*)&lds[S][r_*BK+((kk_*4+lg)^(r_&(GPR-1)))*8]; }     \
      _Pragma("unroll") for(int n_=0;n_<FN;n_++){                           \
        int r_=wn*WN+n_*16+lr;                                              \
        bf_[n_]=*(short8*)&lds[S][BM*BK+r_*BK+((kk_*4+lg)^(r_&(GPR-1)))*8]; } \
      _Pragma("unroll") for(int m_=0;m_<FM;m_++)                            \
        _Pragma("unroll") for(int n_=0;n_<FN;n_++)                          \
          acc[m_][n_]=__builtin_amdgcn_mfma_f32_16x16x32_bf16(af_[m_],bf_[n_],acc[m_][n_],0,0,0); \
  }}while(0)

  #define BODYK(T,S) do{ if((T)<nt){                                        \
    int newer_=imin(nt,(T)+DEPTH)-(T)-1;                                    \
    if(DEPTH>=2 && newer_>=2) wait_vm<2*LPT>();                             \
    else if(newer_>=1) wait_vm<LPT>();                                      \
    else wait_vm<0>();                                                      \
    __builtin_amdgcn_s_barrier();                                           \
    __builtin_amdgcn_sched_barrier(0);                                      \
    STG((T)+DEPTH,((S)+DEPTH)%RING);                                        \
    CMP(S);                                                                 \
  }}while(0)

  STG(0,0);
  if (DEPTH>=2) STG(1,1);
  for (int t=0;t<nt;t+=RING){
    BODYK(t+0,0);
    BODYK(t+1,1);
    if constexpr (RING>=3) BODYK(t+2,2);
  }
  #undef STG
  #undef CMP
  #undef BODYK

  const int rowb = bm + wm*32 + lg*4;
  #pragma unroll
  for (int m=0;m<FM;m++)
    #pragma unroll
    for (int n=0;n<FN;n++){
      int col = bn + wn*WN + n*16 + lr;
      #pragma unroll
      for (int q=0;q<4;q++){
        int row = rowb + m*16 + q;
        if (row < M && col < N){
          float v = acc[m][n][q];
          if (bias) v += bias[col];
          if (OBF16) ((short*)Cv)[(size_t)row*ldc + col] = f2bf(v);
          else       ((float*)Cv)[(size_t)row*ldc + col] = v;
        }
      }
    }
  if (CST){
    #pragma unroll
    for (int n=0;n<FN;n++){
      float s = 0.f, q2 = 0.f;
      #pragma unroll
      for (int m=0;m<FM;m++)
        #pragma unroll
        for (int q=0;q<4;q++){
          int row = rowb + m*16 + q;
          if (row < M){ float v = acc[m][n][q]; s += v; q2 += v*v; }
        }
      s  += __shfl_xor(s, 16);  s += __shfl_xor(s, 32);
      q2 += __shfl_xor(q2, 16); q2 += __shfl_xor(q2, 32);
      if (lg == 0){
        int col = bn + wn*WN + n*16 + lr;
        if (col < N){ atomicAdd(&o_sum[col], s); atomicAdd(&o_sq[col], q2); }
      }
    }
  }
}

// ==================== weight transpose/convert ====================
struct WEnt { const float* src; short* dst; int K, N, KP, NR; };
struct WTab { WEnt e[12]; };
__global__ __launch_bounds__(256) void wtrans_all(WTab tab){
  WEnt w = tab.e[blockIdx.y];
  int gid = blockIdx.x*256 + threadIdx.x;
  if (gid >= w.NR * w.KP) return;
  int n = gid / w.KP, k = gid - n*w.KP;
  float v = (k < w.K && n < w.N) ? w.src[(size_t)k*w.N + n] : 0.f;
  w.dst[gid] = f2bf(v);
}

// ==================== BN (finalize folded) + ELU -> bf16 ====================
template<int C>
__global__ __launch_bounds__(256) void bn_elu_apply2(const float* __restrict__ H, short* __restrict__ O,
    int M, float invM,
    const float* __restrict__ ssum, const float* __restrict__ ssq,
    const float* __restrict__ g, const float* __restrict__ bt){
  __shared__ float sc[C], sh[C];
  for (int c = threadIdx.x; c < C; c += 256){
    float mn  = ssum[c]*invM;
    float var = ssq[c]*invM - mn*mn;
    float s = g[c]*rsqrtf(var + 1e-5f);
    sc[c] = s; sh[c] = bt[c] - mn*s;
  }
  __syncthreads();
  int total4 = M*(C/4);
  for (int i = blockIdx.x*256+threadIdx.x; i < total4; i += gridDim.x*256){
    float4 v = ((const float4*)H)[i];
    int cb = (i*4) & (C-1);
    short4v o;
    o[0] = f2bf(eluf(v.x*sc[cb+0]+sh[cb+0]));
    o[1] = f2bf(eluf(v.y*sc[cb+1]+sh[cb+1]));
    o[2] = f2bf(eluf(v.z*sc[cb+2]+sh[cb+2]));
    o[3] = f2bf(eluf(v.w*sc[cb+3]+sh[cb+3]));
    ((short4v*)O)[i] = o;
  }
}

__global__ __launch_bounds__(256) void bn_elu_split(const float* __restrict__ H,
    short* __restrict__ Od, short* __restrict__ Oc, int M, float invM,
    const float* __restrict__ ssum, const float* __restrict__ ssq,
    const float* __restrict__ gd, const float* __restrict__ btd,
    const float* __restrict__ gc, const float* __restrict__ btc){
  __shared__ float sc[256], sh[256];
  {
    int c = threadIdx.x;
    float mn  = ssum[c]*invM;
    float var = ssq[c]*invM - mn*mn;
    float gg = (c<128) ? gd[c] : gc[c-128];
    float bb = (c<128) ? btd[c] : btc[c-128];
    float s = gg*rsqrtf(var + 1e-5f);
    sc[c] = s; sh[c] = bb - mn*s;
  }
  __syncthreads();
  int total4 = M*64;
  for (int i = blockIdx.x*256+threadIdx.x; i < total4; i += gridDim.x*256){
    float4 v = ((const float4*)H)[i];
    int cb = (i*4) & 255;
    short4v o;
    o[0] = f2bf(eluf(v.x*sc[cb+0]+sh[cb+0]));
    o[1] = f2bf(eluf(v.y*sc[cb+1]+sh[cb+1]));
    o[2] = f2bf(eluf(v.z*sc[cb+2]+sh[cb+2]));
    o[3] = f2bf(eluf(v.w*sc[cb+3]+sh[cb+3]));
    int row = i>>6;
    short* O = (cb < 128) ? Od : Oc;
    *(short4v*)&O[(size_t)row*128 + (cb&127)] = o;
  }
}

// ==================== CSR build ====================
__global__ void hist_kernel(const int* __restrict__ d, int E, int* __restrict__ deg){
  int i = blockIdx.x*256 + threadIdx.x;
  if (i < E) atomicAdd(&deg[d[i]], 1);
}
__global__ __launch_bounds__(256) void scan1(const int* __restrict__ deg, int* __restrict__ offs,
                                             int* __restrict__ bsum, int n){
  __shared__ int sm[256];
  int tid = threadIdx.x;
  int base = blockIdx.x*1024 + tid*4;
  int v0 = base+0<n ? deg[base+0] : 0;
  int v1 = base+1<n ? deg[base+1] : 0;
  int v2 = base+2<n ? deg[base+2] : 0;
  int v3 = base+3<n ? deg[base+3] : 0;
  int ts = v0+v1+v2+v3;
  sm[tid] = ts;
  __syncthreads();
  #pragma unroll
  for (int d=1; d<256; d<<=1){
    int t = (tid>=d) ? sm[tid-d] : 0;
    __syncthreads();
    sm[tid] += t;
    __syncthreads();
  }
  int ex = sm[tid] - ts;
  if (base+0<n) offs[base+0] = ex;
  if (base+1<n) offs[base+1] = ex+v0;
  if (base+2<n) offs[base+2] = ex+v0+v1;
  if (base+3<n) offs[base+3] = ex+v0+v1+v2;
  if (tid==255) bsum[blockIdx.x] = sm[255];
}
__global__ __launch_bounds__(256) void scan3(int* __restrict__ offs, const int* __restrict__ bsum,
                      int* __restrict__ cursor, int n, int total){
  __shared__ int base_sm;
  int tgt = blockIdx.x >> 2;
  if (threadIdx.x < 64){
    int j = threadIdx.x;
    int v = (j < tgt) ? bsum[j] : 0;
    #pragma unroll
    for (int d=32; d; d>>=1) v += __shfl_xor(v, d);
    if (j == 0) base_sm = v;
  }
  __syncthreads();
  int i = blockIdx.x*256 + threadIdx.x;
  if (i < n){ int v = offs[i] + base_sm; offs[i]=v; cursor[i]=v; }
  if (i == 0) offs[n] = total;
}
__global__ void scatter_kernel(const int* __restrict__ s, const int* __restrict__ d, int E,
                               int* __restrict__ cursor, int* __restrict__ csr){
  int i = blockIdx.x*256 + threadIdx.x;
  if (i < E){ int pos = atomicAdd(&cursor[d[i]], 1); csr[pos] = s[i]; }
}

// ==================== GAT1 ====================
__global__ __launch_bounds__(256) void gat1_scores_bf(const short* __restrict__ hh,
    const float* __restrict__ as, const float* __restrict__ ad,
    float* __restrict__ ss, float* __restrict__ sd, int n){
  int w = threadIdx.x >> 6, lane = threadIdx.x & 63;
  int row = blockIdx.x*4 + w;
  if (row >= n) return;
  const short* hr = hh + (size_t)row*192;
  float ps[3], pd[3];
  #pragma unroll
  for (int h=0; h<3; h++){
    float v = b2f(hr[h*64 + lane]);
    ps[h] = v * as[h*64+lane];
    pd[h] = v * ad[h*64+lane];
  }
  #pragma unroll
  for (int m=32; m; m>>=1){
    #pragma unroll
    for (int h=0;h<3;h++){ ps[h] += __shfl_xor(ps[h], m); pd[h] += __shfl_xor(pd[h], m); }
  }
  if (lane == 0){
    #pragma unroll
    for (int h=0;h<3;h++){ ss[row*3+h]=ps[h]; sd[row*3+h]=pd[h]; }
  }
}

__global__ __launch_bounds__(256) void gat1_gather_bf(const int* __restrict__ offs, const int* __restrict__ csr,
    const short* __restrict__ hh, const float* __restrict__ ss, const float* __restrict__ sd,
    const float* __restrict__ bias, short* __restrict__ out, int n){
  int w = threadIdx.x >> 6, lane = threadIdx.x & 63;
  int dst = blockIdx.x*4 + w;
  if (dst >= n) return;
  float sd0 = sd[dst*3+0], sd1 = sd[dst*3+1], sd2 = sd[dst*3+2];
  float p0 = __expf(lrelu(ss[dst*3+0]+sd0));
  float p1 = __expf(lrelu(ss[dst*3+1]+sd1));
  float p2 = __expf(lrelu(ss[dst*3+2]+sd2));
  const short* hr = hh + (size_t)dst*192;
  float a0 = p0*b2f(hr[lane]), a1 = p1*b2f(hr[64+lane]), a2 = p2*b2f(hr[128+lane]);
  float d0 = p0, d1 = p1, d2 = p2;
  int p = offs[dst], pe = offs[dst+1];
  int n0=0,n1=0,n2=0,n3=0;
  if (p+4 <= pe){ n0=csr[p]; n1=csr[p+1]; n2=csr[p+2]; n3=csr[p+3]; }
  while (p+4 <= pe){
    int s0=n0, s1=n1, s2=n2, s3=n3;
    int pn = p+4;
    if (pn+4 <= pe){ n0=csr[pn]; n1=csr[pn+1]; n2=csr[pn+2]; n3=csr[pn+3]; }
    float e00=ss[s0*3+0], e01=ss[s0*3+1], e02=ss[s0*3+2];
    float e10=ss[s1*3+0], e11=ss[s1*3+1], e12=ss[s1*3+2];
    float e20=ss[s2*3+0], e21=ss[s2*3+1], e22=ss[s2*3+2];
    float e30=ss[s3*3+0], e31=ss[s3*3+1], e32=ss[s3*3+2];
    const short* r0 = hh + (size_t)s0*192;
    const short* r1 = hh + (size_t)s1*192;
    const short* r2 = hh + (size_t)s2*192;
    const short* r3 = hh + (size_t)s3*192;
    float v00=b2f(r0[lane]), v01=b2f(r0[64+lane]), v02=b2f(r0[128+lane]);
    float v10=b2f(r1[lane]), v11=b2f(r1[64+lane]), v12=b2f(r1[128+lane]);
    float v20=b2f(r2[lane]), v21=b2f(r2[64+lane]), v22=b2f(r2[128+lane]);
    float v30=b2f(r3[lane]), v31=b2f(r3[64+lane]), v32=b2f(r3[128+lane]);
    float q00=__expf(lrelu(e00+sd0)), q01=__expf(lrelu(e01+sd1)), q02=__expf(lrelu(e02+sd2));
    float q10=__expf(lrelu(e10+sd0)), q11=__expf(lrelu(e11+sd1)), q12=__expf(lrelu(e12+sd2));
    float q20=__expf(lrelu(e20+sd0)), q21=__expf(lrelu(e21+sd1)), q22=__expf(lrelu(e22+sd2));
    float q30=__expf(lrelu(e30+sd0)), q31=__expf(lrelu(e31+sd1)), q32=__expf(lrelu(e32+sd2));
    a0 += q00*v00 + q10*v10 + q20*v20 + q30*v30;
    a1 += q01*v01 + q11*v11 + q21*v21 + q31*v31;
    a2 += q02*v02 + q12*v12 + q22*v22 + q32*v32;
    d0 += q00+q10+q20+q30;
    d1 += q01+q11+q21+q31;
    d2 += q02+q12+q22+q32;
    p = pn;
  }
  for (; p < pe; ++p){
    int src = csr[p];
    float q0 = __expf(lrelu(ss[src*3+0]+sd0));
    float q1 = __expf(lrelu(ss[src*3+1]+sd1));
    float q2 = __expf(lrelu(ss[src*3+2]+sd2));
    const short* sr = hh + (size_t)src*192;
    a0 += q0*b2f(sr[lane]); a1 += q1*b2f(sr[64+lane]); a2 += q2*b2f(sr[128+lane]);
    d0 += q0; d1 += q1; d2 += q2;
  }
  float v0 = a0/d0 + bias[lane];
  float v1 = a1/d1 + bias[64+lane];
  float v2 = a2/d2 + bias[128+lane];
  short* orow = out + (size_t)dst*192;
  orow[lane]      = f2bf(v0 > 0.f ? v0 : 0.f);
  orow[64+lane]   = f2bf(v1 > 0.f ? v1 : 0.f);
  orow[128+lane]  = f2bf(v2 > 0.f ? v2 : 0.f);
}

// ==================== GAT2/3 fused (hh23 [N][64]: cols 0-29 = h2, 32-61 = h3) ====================
__global__ __launch_bounds__(256) void gat23_scores(const float* __restrict__ hh23,
    const float* __restrict__ a2s, const float* __restrict__ a2d,
    const float* __restrict__ a3s, const float* __restrict__ a3d,
    float* __restrict__ s2s, float* __restrict__ s2d, float* __restrict__ s3s, float* __restrict__ s3d, int n){
  int w = threadIdx.x >> 6, lane = threadIdx.x & 63;
  int row = blockIdx.x*4 + w;
  if (row >= n) return;
  float p[4] = {0.f,0.f,0.f,0.f};
  if (lane < 30){
    float v2 = hh23[(size_t)row*64+lane], v3 = hh23[(size_t)row*64+32+lane];
    p[0]=v2*a2s[lane]; p[1]=v2*a2d[lane]; p[2]=v3*a3s[lane]; p[3]=v3*a3d[lane];
  }
  #pragma unroll
  for (int m=32; m; m>>=1){
    #pragma unroll
    for (int j=0;j<4;j++) p[j] += __shfl_xor(p[j], m);
  }
  if (lane == 0){ s2s[row]=p[0]; s2d[row]=p[1]; s3s[row]=p[2]; s3d[row]=p[3]; }
}

__global__ __launch_bounds__(256) void gat23_gather(const int* __restrict__ offs, const int* __restrict__ csr,
    const float* __restrict__ hh23,
    const float* __restrict__ s2s, const float* __restrict__ s2d,
    const float* __restrict__ s3s, const float* __restrict__ s3d,
    const float* __restrict__ b2, const float* __restrict__ b3,
    float* __restrict__ zs, float* __restrict__ mus, float* __restrict__ lvs,
    short* __restrict__ zbf, int n){
  int w = threadIdx.x >> 6, lane = threadIdx.x & 63;
  int dst = blockIdx.x*4 + w;
  if (dst >= n) return;
  bool lo = lane < 32;
  int c = lane & 31;
  bool valid = c < 30;
  float sdA = s2d[dst], sdB = s3d[dst];
  float sdx = lo ? sdA : sdB;
  const float* ssx = lo ? s2s : s3s;
  float p2 = __expf(lrelu(s2s[dst]+sdA));
  float p3 = __expf(lrelu(s3s[dst]+sdB));
  float val = valid ? hh23[(size_t)dst*64+lane] : 0.f;
  float acc = (lo ? p2 : p3) * val;
  float den2 = p2, den3 = p3;
  int p = offs[dst], pe = offs[dst+1];
  int n0=0,n1=0,n2=0,n3=0;
  if (p+4 <= pe){ n0=csr[p]; n1=csr[p+1]; n2=csr[p+2]; n3=csr[p+3]; }
  while (p+4 <= pe){
    int s0=n0, s1=n1, s2i=n2, s3i=n3;
    int pn = p+4;
    if (pn+4 <= pe){ n0=csr[pn]; n1=csr[pn+1]; n2=csr[pn+2]; n3=csr[pn+3]; }
    float eA0=ssx[s0], eA1=ssx[s1], eA2=ssx[s2i], eA3=ssx[s3i];
    float f20=s2s[s0], f21=s2s[s1], f22=s2s[s2i], f23=s2s[s3i];
    float f30=s3s[s0], f31=s3s[s1], f32=s3s[s2i], f33=s3s[s3i];
    float v0 = valid ? hh23[(size_t)s0*64+lane] : 0.f;
    float v1 = valid ? hh23[(size_t)s1*64+lane] : 0.f;
    float v2 = valid ? hh23[(size_t)s2i*64+lane] : 0.f;
    float v3 = valid ? hh23[(size_t)s3i*64+lane] : 0.f;
    float qx0=__expf(lrelu(eA0+sdx)), qx1=__expf(lrelu(eA1+sdx));
    float qx2=__expf(lrelu(eA2+sdx)), qx3=__expf(lrelu(eA3+sdx));
    acc += qx0*v0 + qx1*v1 + qx2*v2 + qx3*v3;
    den2 += __expf(lrelu(f20+sdA)) + __expf(lrelu(f21+sdA)) + __expf(lrelu(f22+sdA)) + __expf(lrelu(f23+sdA));
    den3 += __expf(lrelu(f30+sdB)) + __expf(lrelu(f31+sdB)) + __expf(lrelu(f32+sdB)) + __expf(lrelu(f33+sdB));
    p = pn;
  }
  for (; p < pe; ++p){
    int src = csr[p];
    float q2 = __expf(lrelu(s2s[src]+sdA));
    float q3 = __expf(lrelu(s3s[src]+sdB));
    float v = valid ? hh23[(size_t)src*64+lane] : 0.f;
    acc += (lo ? q2 : q3) * v;
    den2 += q2; den3 += q3;
  }
  if (lo){
    if (valid){
      float v = acc/den2 + b2[c];
      zs[(size_t)dst*30+c]  = v;
      mus[(size_t)dst*30+c] = v;
      zbf[(size_t)dst*64+c] = f2bf(v);
    } else {
      zbf[(size_t)dst*64+c] = 0;
    }
  } else {
    if (valid) lvs[(size_t)dst*30+c] = acc/den3 + b3[c];
    zbf[(size_t)dst*64+32+c] = 0;
  }
}

// ==================== softmax ====================
__global__ __launch_bounds__(256) void softmax10(const float* __restrict__ in, float* __restrict__ out, int n){
  int row = blockIdx.x*256 + threadIdx.x;
  if (row >= n) return;
  const float* r = in + (size_t)row*10;
  float m = r[0];
  #pragma unroll
  for (int j=1;j<10;j++) m = fmaxf(m, r[j]);
  float e[10], s = 0.f;
  #pragma unroll
  for (int j=0;j<10;j++){ e[j] = __expf(r[j]-m); s += e[j]; }
  float inv = 1.f/s;
  float* o = out + (size_t)row*10;
  #pragma unroll
  for (int j=0;j<10;j++) o[j] = e[j]*inv;
}

// ==================== host ====================
static inline int cdiv(int a, int b){ return (a + b - 1) / b; }

extern "C" void kernel_launch(void* const* d_in, const int* in_sizes, int n_in,
                              void* d_out, int out_size, void* d_ws, size_t ws_size,
                              hipStream_t stream)
{
  const float* x        = (const float*)d_in[0];
  const int*   ei       = (const int*)  d_in[1];
  const float* enc_w1   = (const float*)d_in[2];
  const float* enc_g1   = (const float*)d_in[4];
  const float* enc_bt1  = (const float*)d_in[5];
  const float* enc_w2   = (const float*)d_in[6];
  const float* enc_g2   = (const float*)d_in[8];
  const float* enc_bt2  = (const float*)d_in[9];
  const float* gat1_w   = (const float*)d_in[10];
  const float* gat1_as  = (const float*)d_in[11];
  const float* gat1_ad  = (const float*)d_in[12];
  const float* gat1_b   = (const float*)d_in[13];
  const float* gat2_w   = (const float*)d_in[14];
  const float* gat2_as  = (const float*)d_in[15];
  const float* gat2_ad  = (const float*)d_in[16];
  const float* gat2_b   = (const float*)d_in[17];
  const float* gat3_w   = (const float*)d_in[18];
  const float* gat3_as  = (const float*)d_in[19];
  const float* gat3_ad  = (const float*)d_in[20];
  const float* gat3_b   = (const float*)d_in[21];
  const float* dec_w1   = (const float*)d_in[22];
  const float* dec_g1   = (const float*)d_in[24];
  const float* dec_bt1  = (const float*)d_in[25];
  const float* dec_w2   = (const float*)d_in[26];
  const float* dec_g2   = (const float*)d_in[28];
  const float* dec_bt2  = (const float*)d_in[29];
  const float* dec_w3   = (const float*)d_in[30];
  const float* dec_b3   = (const float*)d_in[31];
  const float* clu_w1   = (const float*)d_in[32];
  const float* clu_g1   = (const float*)d_in[34];
  const float* clu_bt1  = (const float*)d_in[35];
  const float* clu_w2   = (const float*)d_in[36];
  const float* clu_b2   = (const float*)d_in[37];

  const int N = in_sizes[0] / 1000;
  const int E = in_sizes[1] / 2;
  const int* e_src = ei;
  const int* e_dst = ei + E;
  const float invN = 1.f/(float)N;

  float* out  = (float*)d_out;
  float* pred = out;
  float* xrec = out + (size_t)N*10;
  float* zs   = xrec + (size_t)N*1000;
  float* mus  = zs  + (size_t)N*30;
  float* lvs  = mus + (size_t)N*30;

  char* ws = (char*)d_ws;
  size_t off = 0;
  auto alloc = [&](size_t bytes)->char*{
    char* p = ws + off;
    off = (off + bytes + 255) & ~(size_t)255;
    return p;
  };
  short* t_enc1  = (short*)alloc(256*1024*2);
  short* t_enc2  = (short*)alloc(128*256*2);
  short* t_gat1  = (short*)alloc(256*128*2);
  short* t_gat23 = (short*)alloc(128*192*2);
  short* t_dc1   = (short*)alloc(256*64*2);
  short* t_dec2  = (short*)alloc(256*128*2);
  short* t_dec3  = (short*)alloc(1024*256*2);
  short* t_clu2  = (short*)alloc(128*128*2);
  float* h1f  = (float*)alloc((size_t)N*256*4);
  short* h1b  = (short*)alloc((size_t)N*256*2);
  float* h2f  = (float*)alloc((size_t)N*128*4);
  short* h2b  = (short*)alloc((size_t)N*128*2);
  short* hh1b = (short*)alloc((size_t)N*192*2);
  short* h3b  = (short*)alloc((size_t)N*192*2);
  float* hh23f= (float*)alloc((size_t)N*64*4);
  short* zbf  = (short*)alloc((size_t)N*64*2);
  float* ss1  = (float*)alloc((size_t)N*3*4);
  float* sd1  = (float*)alloc((size_t)N*3*4);
  float* s2s  = (float*)alloc((size_t)N*4);
  float* s2d  = (float*)alloc((size_t)N*4);
  float* s3s  = (float*)alloc((size_t)N*4);
  float* s3d  = (float*)alloc((size_t)N*4);
  float* stats= (float*)alloc(2048*4);
  int*   deg  = (int*)alloc((size_t)(N+1)*4);
  int*   offs = (int*)alloc((size_t)(N+1)*4);
  int*   curp = (int*)alloc((size_t)(N+1)*4);
  int*   bsum = (int*)alloc(256*4);
  int*   csr  = (int*)alloc((size_t)E*4);
  // aliases (lifetimes):
  short* xb   = h1b;               // [N][1000] bf16 spans h1b..h3b (102.4MB); dead after enc1 gemm
  float* dc1f = h2f;               // [N][256] f32 spans h2f+h2b+hh1b (57.6MB); live after gat1_gather
  short* d1b  = h3b;               // [N][128] bf16; h3b dead after gat23 gemm
  short* c1b  = (short*)hh23f;     // [N][128] bf16 (12.8MB == hh23f); dead after gat23 gather
  float* d2f  = h1f;               // [N][256] f32; h1f dead after enc2 gemm
  short* d2b  = h1b;               // [N][256] bf16; h1b dead after enc2 gemm
  float* c2   = (float*)zbf;       // [N][10] f32 (2MB <= 6.4MB); zbf dead after dc1 gemm
  float* st_enc1 = stats, *st_enc2 = stats+512, *st_dc1 = stats+768, *st_dec2 = stats+1280;

  // --- weight prep + zeroing ---
  WTab tab;
  tab.e[0]  = {enc_w1, t_enc1, 1000, 256, 1024, 256};
  tab.e[1]  = {enc_w2, t_enc2, 256, 128, 256, 128};
  tab.e[2]  = {gat1_w, t_gat1, 128, 192, 128, 256};
  tab.e[3]  = {gat2_w, t_gat23, 192, 30, 192, 32};
  tab.e[4]  = {gat3_w, t_gat23 + 32*192, 192, 30, 192, 32};
  tab.e[5]  = {gat2_w, t_gat23 + 64*192, 192, 0, 192, 64};   // zero rows 64-127
  tab.e[6]  = {dec_w1, t_dc1, 30, 128, 64, 128};
  tab.e[7]  = {clu_w1, t_dc1 + 128*64, 30, 128, 64, 128};
  tab.e[8]  = {dec_w2, t_dec2, 128, 256, 128, 256};
  tab.e[9]  = {dec_w3, t_dec3, 256, 1000, 256, 1024};
  tab.e[10] = {clu_w2, t_clu2, 128, 10, 128, 128};
  tab.e[11] = {enc_w1, t_enc1, 0, 0, 0, 0};                  // dummy
  wtrans_all<<<dim3(1024, 12), 256, 0, stream>>>(tab);
  hipMemsetAsync(stats, 0, 2048*4, stream);
  hipMemsetAsync(deg, 0, (size_t)(N+1)*4, stream);

  // --- CSR ---
  hist_kernel<<<cdiv(E,256), 256, 0, stream>>>(e_dst, E, deg);
  int nb = cdiv(N, 1024);
  scan1<<<nb, 256, 0, stream>>>(deg, offs, bsum, N);
  scan3<<<cdiv(N,256), 256, 0, stream>>>(offs, bsum, curp, N, E);
  scatter_kernel<<<cdiv(E,256), 256, 0, stream>>>(e_src, e_dst, E, curp, csr);

  const int MB = cdiv(N, 128);

  // --- encoder L1: cvt + BN=256 ring-3 (A read once) ---
  cvt_x<<<cdiv(N,2), 256, 0, stream>>>(x, xb, N);
  gemm_k<256,64,3,false,true><<<dim3(MB,1), 512, 0, stream>>>(
      xb, 1000, t_enc1, 1024, h1f, 256, nullptr, N, 256, 1000, st_enc1, st_enc1+256);
  bn_elu_apply2<256><<<2048, 256, 0, stream>>>(h1f, h1b, N, invN, st_enc1, st_enc1+256, enc_g1, enc_bt1);

  // --- encoder L2 ---
  gemm_k<128,64,2,false,true><<<dim3(MB,1), 512, 0, stream>>>(
      h1b, 256, t_enc2, 256, h2f, 128, nullptr, N, 128, 256, st_enc2, st_enc2+128);
  bn_elu_apply2<128><<<2048, 256, 0, stream>>>(h2f, h2b, N, invN, st_enc2, st_enc2+128, enc_g2, enc_bt2);

  // --- GAT1 ---
  gemm_k<128,64,2,true,false><<<dim3(MB,2), 512, 0, stream>>>(
      h2b, 128, t_gat1, 128, hh1b, 192, nullptr, N, 192, 128, nullptr, nullptr);
  gat1_scores_bf<<<cdiv(N,4), 256, 0, stream>>>(hh1b, gat1_as, gat1_ad, ss1, sd1, N);
  gat1_gather_bf<<<cdiv(N,4), 256, 0, stream>>>(offs, csr, hh1b, ss1, sd1, gat1_b, h3b, N);

  // --- GAT2+GAT3 (combined) ---
  gemm_k<128,64,2,false,false><<<dim3(MB,1), 512, 0, stream>>>(
      h3b, 192, t_gat23, 192, hh23f, 64, nullptr, N, 64, 192, nullptr, nullptr);
  gat23_scores<<<cdiv(N,4), 256, 0, stream>>>(hh23f, gat2_as, gat2_ad, gat3_as, gat3_ad, s2s, s2d, s3s, s3d, N);
  gat23_gather<<<cdiv(N,4), 256, 0, stream>>>(offs, csr, hh23f, s2s, s2d, s3s, s3d, gat2_b, gat3_b, zs, mus, lvs, zbf, N);

  // --- dec1 + clu1 combined ---
  gemm_k<128,64,2,false,true><<<dim3(MB,2), 512, 0, stream>>>(
      zbf, 64, t_dc1, 64, dc1f, 256, nullptr, N, 256, 32, st_dc1, st_dc1+256);
  bn_elu_split<<<2048, 256, 0, stream>>>(dc1f, d1b, c1b, N, invN, st_dc1, st_dc1+256, dec_g1, dec_bt1, clu_g1, clu_bt1);

  // --- dec2 ---
  gemm_k<128,64,2,false,true><<<dim3(MB,2), 512, 0, stream>>>(
      d1b, 128, t_dec2, 128, d2f, 256, nullptr, N, 256, 128, st_dec2, st_dec2+256);
  bn_elu_apply2<256><<<2048, 256, 0, stream>>>(d2f, d2b, N, invN, st_dec2, st_dec2+256, dec_g2, dec_bt2);

  // --- dec3 ---
  gemm_k<128,64,2,false,false><<<dim3(MB,8), 512, 0, stream>>>(
      d2b, 256, t_dec3, 256, xrec, 1000, dec_b3, N, 1000, 256, nullptr, nullptr);

  // --- clu2 + softmax ---
  gemm_k<128,64,2,false,false><<<dim3(MB,1), 512, 0, stream>>>(
      c1b, 128, t_clu2, 128, c2, 10, clu_b2, N, 10, 128, nullptr, nullptr);
  softmax10<<<cdiv(N,256), 256, 0, stream>>>(c2, pred, N);
}